// Round 1
// baseline (56.614 us; speedup 1.0000x reference)
//
#include <hip/hip_runtime.h>
#include <math.h>

// Chamfer loss: B=4, N=M=8192, 3-D fp32 points.
// final = (1/(B*N)) * sum_{b,i} max(min_j d2(x_bi, y_bj), 0)
//       + (1/(B*M)) * sum_{b,j} max(min_i d2(...), 0)
//       + lam * mean(fbpp)
// Per-pair math uses min_j(y2_j - 2 x.y_j) + x2  (5 VALU ops/pair).

#define TILE   2048   // y-points staged per LDS tile (32 KB as float4)
#define SPLITS 16     // waves per block, each handles a 1/16 stride of y
#define IX     4      // x-points per thread
#define PTS    256    // x-points per block = 64 lanes * IX

__global__ __launch_bounds__(1024) void chamfer_min_kernel(
    const float* __restrict__ pred, const float* __restrict__ targ,
    int B, int N, int M, float* __restrict__ partial)
{
    const int dir = blockIdx.z;          // 0: pred->targ, 1: targ->pred
    const int b   = blockIdx.y;

    const float* __restrict__ xs = (dir == 0) ? pred : targ;
    const float* __restrict__ ys = (dir == 0) ? targ : pred;
    const int Nx = (dir == 0) ? N : M;   // # x-points (outer)
    const int My = (dir == 0) ? M : N;   // # y-points (inner min)

    const int tid  = threadIdx.x;
    const int s    = tid >> 6;           // wave index = split 0..15
    const int lane = tid & 63;

    __shared__ float4 yt[TILE];          // 32 KB
    __shared__ float  red[SPLITS][PTS];  // 16 KB

    // ---- load this thread's IX x-points ----
    const int p0 = blockIdx.x * PTS + lane * IX;
    float px[IX], py[IX], pz[IX], n2x[IX];
    bool  valid[IX];
    #pragma unroll
    for (int k = 0; k < IX; ++k) {
        const int p = p0 + k;
        valid[k] = (p < Nx);
        if (valid[k]) {
            const float* xp = xs + ((size_t)b * Nx + p) * 3;
            px[k] = xp[0]; py[k] = xp[1]; pz[k] = xp[2];
            n2x[k] = px[k]*px[k] + py[k]*py[k] + pz[k]*pz[k];
        } else {
            px[k] = py[k] = pz[k] = n2x[k] = 0.0f;
        }
    }

    float best[IX];
    #pragma unroll
    for (int k = 0; k < IX; ++k) best[k] = INFINITY;

    // ---- main loop over y tiles ----
    for (int t0 = 0; t0 < My; t0 += TILE) {
        const int cnt = min(TILE, My - t0);

        // stage cnt y-points as float4(x,y,z,|y|^2)
        for (int idx = tid; idx < cnt; idx += 1024) {
            const float* yp = ys + ((size_t)b * My + t0 + idx) * 3;
            const float a = yp[0], c = yp[1], d = yp[2];
            yt[idx] = make_float4(a, c, d, a*a + c*c + d*d);
        }
        __syncthreads();

        // each wave strides over its 1/SPLITS share; address is
        // lane-uniform -> ds_read_b128 broadcast, no bank conflicts
        #pragma unroll 4
        for (int jj = s; jj < cnt; jj += SPLITS) {
            const float4 q = yt[jj];
            #pragma unroll
            for (int k = 0; k < IX; ++k) {
                const float dot = fmaf(q.x, px[k],
                                  fmaf(q.y, py[k], q.z * pz[k]));
                const float v   = fmaf(dot, -2.0f, q.w);  // y2 - 2 x.y
                best[k] = fminf(best[k], v);
            }
        }
        __syncthreads();
    }

    // ---- per-point value (add |x|^2, clamp >= 0); invalid -> 0 ----
    #pragma unroll
    for (int k = 0; k < IX; ++k) {
        const float v = valid[k] ? fmaxf(best[k] + n2x[k], 0.0f) : 0.0f;
        red[s][lane * IX + k] = v;
    }
    __syncthreads();

    // min across the 16 splits for each of the 256 points
    if (tid < PTS) {
        float m = red[0][tid];
        #pragma unroll
        for (int s2 = 1; s2 < SPLITS; ++s2) m = fminf(m, red[s2][tid]);
        red[0][tid] = m;
    }
    __syncthreads();

    // sum the 256 per-point mins (deterministic tree)
    for (int off = PTS / 2; off > 0; off >>= 1) {
        if (tid < off) red[0][tid] += red[0][tid + off];
        __syncthreads();
    }

    if (tid == 0) {
        const size_t flat = ((size_t)dir * gridDim.y + b) * gridDim.x
                            + blockIdx.x;
        partial[flat] = red[0][0];
    }
}

__global__ void finalize_kernel(const float* __restrict__ partial,
                                int ntot, int half,
                                float invBN, float invBM,
                                const float* __restrict__ fbpp, int Bf,
                                const void* __restrict__ lamp,
                                float* __restrict__ out)
{
    __shared__ float sb[256];
    const int tid = threadIdx.x;
    float acc = 0.0f;
    for (int i = tid; i < ntot; i += 256)
        acc += partial[i] * (i < half ? invBN : invBM);
    sb[tid] = acc;
    __syncthreads();
    for (int off = 128; off > 0; off >>= 1) {
        if (tid < off) sb[tid] += sb[tid + off];
        __syncthreads();
    }
    if (tid == 0) {
        // lam may arrive as int32 or float32 bits; decode defensively
        const int li = *(const int*)lamp;
        const float lam = (li >= -1000000 && li <= 1000000)
                            ? (float)li : *(const float*)lamp;
        float fm = 0.0f;
        for (int i = 0; i < Bf; ++i) fm += fbpp[i];
        fm /= (float)Bf;
        out[0] = sb[0] + lam * fm;
    }
}

extern "C" void kernel_launch(void* const* d_in, const int* in_sizes, int n_in,
                              void* d_out, int out_size, void* d_ws, size_t ws_size,
                              hipStream_t stream) {
    const float* pred = (const float*)d_in[0];
    const float* targ = (const float*)d_in[1];
    const float* fbpp = (const float*)d_in[2];
    const void*  lamp = d_in[3];

    const int B = in_sizes[2];
    const int N = in_sizes[0] / (3 * B);
    const int M = in_sizes[1] / (3 * B);

    float* partial = (float*)d_ws;

    const int nmax = (N > M) ? N : M;
    const int gx = (nmax + PTS - 1) / PTS;
    dim3 grid(gx, B, 2), block(1024);
    chamfer_min_kernel<<<grid, block, 0, stream>>>(pred, targ, B, N, M,
                                                   partial);

    const int half = gx * B;
    const int ntot = 2 * half;
    finalize_kernel<<<1, 256, 0, stream>>>(partial, ntot, half,
                                           1.0f / ((float)B * (float)N),
                                           1.0f / ((float)B * (float)M),
                                           fbpp, B, lamp, (float*)d_out);
}